// Round 3
// baseline (314.401 us; speedup 1.0000x reference)
//
#include <hip/hip_runtime.h>

// SNN leaky integrate-and-fire, two roofline-shaped kernels.
// x: [65536, 784] f32, W: [1, 784] f32.
// out = concat(spk_rec [255,65536], mem_rec [255,65536]) f32.
//
// K1 (read-bound): one WAVE per row, 65536 waves. Coalesced float4 loads,
//     f64 dot + shuffle reduce -> cur[row] (f64) in d_ws. ~205 MB read.
// K2 (write-bound): time-split recurrence. Thread (row, chunk) replays
//     steps 1..32k from mem0=0 (bit-identical fma chain -> same values as a
//     single sequential pass), then stores its own 32-step window.
//     8192 waves (vs 1024 thread-per-row) -> store stream at HBM rate.

#define NROWS   65536
#define DIM     784            // = 196 float4
#define STEPS   255
#define BETA    0.95
#define CHUNK   32             // steps per K2 thread (last chunk: 31)
#define NCHUNK  8              // 8*32 - 1 = 255

// ---- Kernel 1: cur[row] = dot(x[row], W), f64 accumulate ----
__global__ __launch_bounds__(256) void snn_matvec(const float* __restrict__ x,
                                                  const float* __restrict__ W,
                                                  double* __restrict__ cur) {
    const int lane = threadIdx.x & 63;
    const long long row = (long long)blockIdx.x * 4 + (threadIdx.x >> 6);

    const float4* __restrict__ W4 = (const float4*)W;
    const float4* __restrict__ xr = (const float4*)(x + row * DIM);

    // 196 float4 per row: lanes 0..63 take chunks l, l+64, l+128; lanes 0..3 tail.
    float4 a0 = xr[lane];
    float4 a1 = xr[lane + 64];
    float4 a2 = xr[lane + 128];
    float4 w0 = W4[lane];
    float4 w1 = W4[lane + 64];
    float4 w2 = W4[lane + 128];
    float4 a3 = make_float4(0.f, 0.f, 0.f, 0.f);
    float4 w3 = make_float4(0.f, 0.f, 0.f, 0.f);
    if (lane < 4) { a3 = xr[192 + lane]; w3 = W4[192 + lane]; }

    double s = (double)a0.x * (double)w0.x + (double)a0.y * (double)w0.y
             + (double)a0.z * (double)w0.z + (double)a0.w * (double)w0.w
             + (double)a1.x * (double)w1.x + (double)a1.y * (double)w1.y
             + (double)a1.z * (double)w1.z + (double)a1.w * (double)w1.w
             + (double)a2.x * (double)w2.x + (double)a2.y * (double)w2.y
             + (double)a2.z * (double)w2.z + (double)a2.w * (double)w2.w
             + (double)a3.x * (double)w3.x + (double)a3.y * (double)w3.y
             + (double)a3.z * (double)w3.z + (double)a3.w * (double)w3.w;

    #pragma unroll
    for (int off = 32; off > 0; off >>= 1)
        s += __shfl_down(s, off, 64);

    if (lane == 0) cur[row] = s;
}

// one recurrence step; explicit fma pins rounding so every replay is
// bit-identical to the sequential chain
__device__ __forceinline__ double snn_step(double mem, double cur) {
    return (mem > 1.0) ? 0.0 : fma(BETA, mem, cur);
}

// ---- Kernel 2: time-split recurrence ----
// grid: (NROWS/256) * NCHUNK blocks of 256 threads.
// block b: chunk = b / (NROWS/256), rowBase = (b % (NROWS/256)) * 256
// -> chunk is block-uniform (no divergence), rows contiguous (coalesced).
__global__ __launch_bounds__(256) void snn_recur(const double* __restrict__ curBuf,
                                                 float* __restrict__ out) {
    const int rowBlocks = NROWS / 256;
    const int chunk = blockIdx.x / rowBlocks;
    const long long row = (long long)(blockIdx.x % rowBlocks) * 256 + threadIdx.x;

    const double cur = curBuf[row];
    double mem = 0.0;

    // warm-up: replay steps t = 1 .. 32*chunk (no stores)
    const int warm = CHUNK * chunk;
    #pragma unroll 4
    for (int i = 0; i < warm; ++i)
        mem = snn_step(mem, cur);

    // stored window: steps t = warm+1 .. warm+nst  -> out index t-1
    const int nst = (chunk == NCHUNK - 1) ? (CHUNK - 1) : CHUNK;
    float* __restrict__ spkOut = out + (long long)warm * NROWS + row;
    float* __restrict__ memOut = out + (long long)(STEPS + warm) * NROWS + row;

    for (int i = 0; i < nst; ++i) {
        mem = snn_step(mem, cur);
        __builtin_nontemporal_store((mem > 1.0) ? 1.0f : 0.0f, spkOut);
        __builtin_nontemporal_store((float)mem, memOut);
        spkOut += NROWS;
        memOut += NROWS;
    }
}

extern "C" void kernel_launch(void* const* d_in, const int* in_sizes, int n_in,
                              void* d_out, int out_size, void* d_ws, size_t ws_size,
                              hipStream_t stream) {
    const float* x = (const float*)d_in[0];   // [65536, 784]
    const float* W = (const float*)d_in[1];   // [1, 784]
    float* out = (float*)d_out;               // spk (255*65536) then mem (255*65536)
    double* cur = (double*)d_ws;              // 65536 * 8 B = 512 KB scratch

    hipLaunchKernelGGL(snn_matvec, dim3(NROWS / 4), dim3(256), 0, stream, x, W, cur);
    hipLaunchKernelGGL(snn_recur, dim3((NROWS / 256) * NCHUNK), dim3(256), 0, stream,
                       cur, out);
}